// Round 1
// baseline (218.938 us; speedup 1.0000x reference)
//
#include <hip/hip_runtime.h>

// Problem geometry (fixed by the reference file).
constexpr int B = 16;
constexpr int V = 16384;       // variants per batch
constexpr int G = 20000;       // genes
constexpr int D = 64;          // embedding dim
constexpr long long OUT_N = (long long)B * G * D;   // 20,480,000 floats

// Monotone order-preserving float32 <-> uint32 mapping:
// enc(f) is strictly increasing in f; sentinel 0 is below enc(x) for every
// real float x (only -NaN encodes below enc(-inf)=0x007FFFFF; data is normal).
__device__ __forceinline__ unsigned int enc_f32(float f) {
  unsigned int u = __float_as_uint(f);
  return (u & 0x80000000u) ? ~u : (u | 0x80000000u);
}
__device__ __forceinline__ float dec_f32(unsigned int e) {
  unsigned int u = (e & 0x80000000u) ? (e ^ 0x80000000u) : ~u ? ~e : ~e;
  return __uint_as_float(u);
}

// Pass 1: zero the output buffer (viewed as uint32 sentinels).
__global__ void ga_init(uint4* __restrict__ out4, int n4) {
  int stride = gridDim.x * blockDim.x;
  for (int i = blockIdx.x * blockDim.x + threadIdx.x; i < n4; i += stride) {
    out4[i] = make_uint4(0u, 0u, 0u, 0u);
  }
}

// Pass 2: scatter-max. One thread per (variant, 4-dim chunk).
// Thread tid: variant v = tid>>4, dim-quad dq = tid&15.
// emb4 is [B*V][16] float4 (contiguous) -> emb4[tid] is fully coalesced.
__global__ void ga_scatter(const float4* __restrict__ emb4,
                           const int* __restrict__ gene_ids,
                           const int* __restrict__ mask,
                           unsigned int* __restrict__ out) {
  int tid = blockIdx.x * blockDim.x + threadIdx.x;   // 0 .. B*V*16-1
  int v  = tid >> 4;
  int dq = tid & 15;
  if (!mask[v]) return;
  int g = gene_ids[v];
  int b = v >> 14;                                   // v / V (V = 16384)
  float4 e = emb4[tid];
  int base = (b * G + g) * D + (dq << 2);            // < 20.48M, fits int32
  atomicMax(out + base + 0, enc_f32(e.x));
  atomicMax(out + base + 1, enc_f32(e.y));
  atomicMax(out + base + 2, enc_f32(e.z));
  atomicMax(out + base + 3, enc_f32(e.w));
}

// Pass 3: in-place decode; sentinel 0 (no variant touched) -> 0.0f.
__global__ void ga_finalize(uint4* __restrict__ io4, int n4) {
  int stride = gridDim.x * blockDim.x;
  for (int i = blockIdx.x * blockDim.x + threadIdx.x; i < n4; i += stride) {
    uint4 e = io4[i];
    float4 f;
    f.x = e.x ? dec_f32(e.x) : 0.0f;
    f.y = e.y ? dec_f32(e.y) : 0.0f;
    f.z = e.z ? dec_f32(e.z) : 0.0f;
    f.w = e.w ? dec_f32(e.w) : 0.0f;
    *reinterpret_cast<float4*>(io4 + i) = f;
  }
}

extern "C" void kernel_launch(void* const* d_in, const int* in_sizes, int n_in,
                              void* d_out, int out_size, void* d_ws, size_t ws_size,
                              hipStream_t stream) {
  const float4* emb4      = (const float4*)d_in[0];        // [B,V,D] f32
  const int*    gene_ids  = (const int*)d_in[1];           // [B,V] (int64 -> int32 by harness)
  const int*    mask      = (const int*)d_in[2];           // [B,V] bool -> int32 by harness
  unsigned int* out_u     = (unsigned int*)d_out;          // [B,G,D] f32 out, used as u32 scratch

  const int n4 = (int)(OUT_N / 4);                         // 5,120,000 uint4s
  ga_init<<<2048, 256, 0, stream>>>((uint4*)d_out, n4);

  const int nthreads = B * V * (D / 4);                    // 4,194,304
  ga_scatter<<<nthreads / 256, 256, 0, stream>>>(emb4, gene_ids, mask, out_u);

  ga_finalize<<<2048, 256, 0, stream>>>((uint4*)d_out, n4);
}

// Round 2
// 53.855 us; speedup vs baseline: 4.0653x; 4.0653x over previous
//
#include <hip/hip_runtime.h>

// Problem geometry (fixed by the reference file).
constexpr int B = 16;
constexpr int V = 16384;                 // variants per batch
constexpr int G = 20000;                 // genes
constexpr int D = 64;                    // embedding dim
constexpr int NCELLS = B * G;            // 320,000 output cells
constexpr int NROWS  = B * V;            // 262,144 variant rows
constexpr int OVF_MAX = 16384;           // overflow list capacity (entries)
constexpr long long OUT_N = (long long)NCELLS * D;   // 20,480,000 floats

// ------------------------- counting-sort gather path -------------------------
// ws layout (u32 units):
//   [0, NCELLS)                         counts per cell
//   [NCELLS]                            overflow counter
//   [NCELLS+1, NCELLS+1+2*OVF_MAX)      overflow list: (cell, row) pairs
//   [LISTS_OFF, LISTS_OFF+NCELLS*CAP)   per-cell row-id lists
constexpr int OVF_HDR   = NCELLS;
constexpr int OVF_LIST  = NCELLS + 1;
constexpr int LISTS_OFF = NCELLS + 1 + 2 * OVF_MAX;

__global__ void ga_zero(unsigned int* __restrict__ ws, int n) {
  int stride = gridDim.x * blockDim.x;
  for (int i = blockIdx.x * blockDim.x + threadIdx.x; i < n; i += stride)
    ws[i] = 0u;
}

__global__ void ga_build(const int* __restrict__ gene_ids,
                         const int* __restrict__ mask,
                         unsigned int* __restrict__ ws, int cap) {
  int r = blockIdx.x * blockDim.x + threadIdx.x;   // global variant row
  if (r >= NROWS) return;
  if (!mask[r]) return;
  int b = r >> 14;                                 // r / V
  int cell = b * G + gene_ids[r];
  unsigned int pos = atomicAdd(&ws[cell], 1u);
  if (pos < (unsigned int)cap) {
    ws[LISTS_OFF + (size_t)cell * cap + pos] = (unsigned int)r;
  } else {
    unsigned int o = atomicAdd(&ws[OVF_HDR], 1u);
    if (o < (unsigned int)OVF_MAX) {
      ws[OVF_LIST + 2 * o + 0] = (unsigned int)cell;
      ws[OVF_LIST + 2 * o + 1] = (unsigned int)r;
    }
  }
}

// 16 threads per cell; thread owns one float4 (4 dims). Row loads are 256 B
// contiguous per cell; each embedding row is read exactly once chip-wide.
__global__ void ga_gather(const float4* __restrict__ emb4,
                          const unsigned int* __restrict__ ws,
                          float4* __restrict__ out4, int cap) {
  int t = blockIdx.x * blockDim.x + threadIdx.x;
  int cell = t >> 4;
  int sub  = t & 15;
  if (cell >= NCELLS) return;
  unsigned int c = ws[cell];
  int n = (int)(c < (unsigned int)cap ? c : (unsigned int)cap);
  const unsigned int* lp = ws + LISTS_OFF + (size_t)cell * cap;
  float ninf = -__builtin_inff();
  float4 acc = make_float4(ninf, ninf, ninf, ninf);
  for (int k = 0; k < n; ++k) {
    unsigned int row = lp[k];
    float4 v = emb4[(size_t)row * 16 + sub];
    acc.x = fmaxf(acc.x, v.x);
    acc.y = fmaxf(acc.y, v.y);
    acc.z = fmaxf(acc.z, v.z);
    acc.w = fmaxf(acc.w, v.w);
  }
  if (c == 0u) acc = make_float4(0.f, 0.f, 0.f, 0.f);
  out4[(size_t)cell * 16 + sub] = acc;
}

__device__ __forceinline__ void atomic_max_float(float* addr, float val) {
  unsigned int* ua = (unsigned int*)addr;
  unsigned int old = *ua;
  while (__uint_as_float(old) < val) {
    unsigned int assumed = old;
    old = atomicCAS(ua, assumed, __float_as_uint(val));
    if (old == assumed) break;
  }
}

// Drain overflow entries (expected: zero or a handful).
__global__ void ga_ovf(const float4* __restrict__ emb4,
                       const unsigned int* __restrict__ ws,
                       float* __restrict__ out) {
  unsigned int nov = ws[OVF_HDR];
  if (nov > (unsigned int)OVF_MAX) nov = OVF_MAX;
  int total = (int)nov * 16;
  int stride = gridDim.x * blockDim.x;
  for (int u = blockIdx.x * blockDim.x + threadIdx.x; u < total; u += stride) {
    int e = u >> 4, sub = u & 15;
    unsigned int cell = ws[OVF_LIST + 2 * e + 0];
    unsigned int row  = ws[OVF_LIST + 2 * e + 1];
    float4 v = emb4[(size_t)row * 16 + sub];
    float* o = out + (size_t)cell * 64 + sub * 4;
    atomic_max_float(o + 0, v.x);
    atomic_max_float(o + 1, v.y);
    atomic_max_float(o + 2, v.z);
    atomic_max_float(o + 3, v.w);
  }
}

// ------------------------- legacy atomic path (ws too small) -----------------
__device__ __forceinline__ unsigned int enc_f32(float f) {
  unsigned int u = __float_as_uint(f);
  return (u & 0x80000000u) ? ~u : (u | 0x80000000u);
}
__device__ __forceinline__ float dec_f32(unsigned int e) {
  unsigned int u = (e & 0x80000000u) ? (e ^ 0x80000000u) : ~e;
  return __uint_as_float(u);
}

__global__ void ga_init(uint4* __restrict__ out4, int n4) {
  int stride = gridDim.x * blockDim.x;
  for (int i = blockIdx.x * blockDim.x + threadIdx.x; i < n4; i += stride)
    out4[i] = make_uint4(0u, 0u, 0u, 0u);
}

__global__ void ga_scatter(const float4* __restrict__ emb4,
                           const int* __restrict__ gene_ids,
                           const int* __restrict__ mask,
                           unsigned int* __restrict__ out) {
  int tid = blockIdx.x * blockDim.x + threadIdx.x;
  int v  = tid >> 4;
  int dq = tid & 15;
  if (!mask[v]) return;
  int g = gene_ids[v];
  int b = v >> 14;
  float4 e = emb4[tid];
  int base = (b * G + g) * D + (dq << 2);
  atomicMax(out + base + 0, enc_f32(e.x));
  atomicMax(out + base + 1, enc_f32(e.y));
  atomicMax(out + base + 2, enc_f32(e.z));
  atomicMax(out + base + 3, enc_f32(e.w));
}

__global__ void ga_finalize(uint4* __restrict__ io4, int n4) {
  int stride = gridDim.x * blockDim.x;
  for (int i = blockIdx.x * blockDim.x + threadIdx.x; i < n4; i += stride) {
    uint4 e = io4[i];
    float4 f;
    f.x = e.x ? dec_f32(e.x) : 0.0f;
    f.y = e.y ? dec_f32(e.y) : 0.0f;
    f.z = e.z ? dec_f32(e.z) : 0.0f;
    f.w = e.w ? dec_f32(e.w) : 0.0f;
    *reinterpret_cast<float4*>(io4 + i) = f;
  }
}

// -----------------------------------------------------------------------------
extern "C" void kernel_launch(void* const* d_in, const int* in_sizes, int n_in,
                              void* d_out, int out_size, void* d_ws, size_t ws_size,
                              hipStream_t stream) {
  const float4* emb4     = (const float4*)d_in[0];   // [B,V,D] f32
  const int*    gene_ids = (const int*)d_in[1];      // [B,V]
  const int*    mask     = (const int*)d_in[2];      // [B,V]

  // Pick the largest list capacity (<=16) that fits in ws.
  long long ws_u32 = (long long)(ws_size / 4);
  long long avail  = ws_u32 - (long long)LISTS_OFF;
  int cap = (int)(avail > 0 ? avail / NCELLS : 0);
  if (cap > 16) cap = 16;

  if (cap >= 6) {
    unsigned int* ws = (unsigned int*)d_ws;
    // zero counts + overflow header (lists need no init)
    ga_zero<<<512, 256, 0, stream>>>(ws, NCELLS + 1);
    ga_build<<<NROWS / 256, 256, 0, stream>>>(gene_ids, mask, ws, cap);
    ga_gather<<<(int)(OUT_N / 4 / 256), 256, 0, stream>>>(
        emb4, ws, (float4*)d_out, cap);
    ga_ovf<<<64, 256, 0, stream>>>(emb4, ws, (float*)d_out);
  } else {
    // Fallback: direct atomic scatter-max (previous passing version).
    unsigned int* out_u = (unsigned int*)d_out;
    const int n4 = (int)(OUT_N / 4);
    ga_init<<<2048, 256, 0, stream>>>((uint4*)d_out, n4);
    ga_scatter<<<(NROWS * 16) / 256, 256, 0, stream>>>(emb4, gene_ids, mask, out_u);
    ga_finalize<<<2048, 256, 0, stream>>>((uint4*)d_out, n4);
  }
}

// Round 3
// 49.636 us; speedup vs baseline: 4.4109x; 1.0850x over previous
//
#include <hip/hip_runtime.h>

// Problem geometry (fixed by the reference file).
constexpr int B = 16;
constexpr int V = 16384;                 // variants per batch
constexpr int G = 20000;                 // genes
constexpr int D = 64;                    // embedding dim
constexpr int NCELLS = B * G;            // 320,000 output cells
constexpr int NROWS  = B * V;            // 262,144 variant rows
constexpr int OVF_MAX = 16384;
constexpr long long OUT_N = (long long)NCELLS * D;   // 20,480,000 floats

// ---------------------------- header+spill layout ----------------------------
// ws layout (u32 units):
//   [0, 4*NCELLS)                       headers: {count, r0, r1, r2} per cell
//   [OVF_HDR]                           overflow counter
//   [OVF_LIST, OVF_LIST+2*OVF_MAX)     overflow (cell,row) pairs
//   [SPILL_OFF, SPILL_OFF+NCELLS*SCAP) spill rows (rows 3..3+SCAP-1 per cell)
constexpr int HDR_WORDS = 4 * NCELLS;
constexpr int OVF_HDR   = HDR_WORDS;
constexpr int OVF_LIST  = HDR_WORDS + 1;
constexpr int SPILL_OFF = HDR_WORDS + 1 + 2 * OVF_MAX;

__global__ void ga_zero(uint4* __restrict__ ws4, unsigned int* __restrict__ ws) {
  int stride = gridDim.x * blockDim.x;
  for (int i = blockIdx.x * blockDim.x + threadIdx.x; i < HDR_WORDS / 4; i += stride)
    ws4[i] = make_uint4(0u, 0u, 0u, 0u);
  if (blockIdx.x == 0 && threadIdx.x == 0) ws[OVF_HDR] = 0u;
}

__global__ void ga_build(const int* __restrict__ gene_ids,
                         const int* __restrict__ mask,
                         unsigned int* __restrict__ ws, int scap) {
  int r = blockIdx.x * blockDim.x + threadIdx.x;   // global variant row
  if (r >= NROWS) return;
  if (!mask[r]) return;
  int cell = (r >> 14) * G + gene_ids[r];          // r>>14 == batch
  unsigned int pos = atomicAdd(&ws[cell * 4], 1u);
  if (pos < 3u) {
    ws[cell * 4 + 1 + pos] = (unsigned int)r;
  } else if (pos < 3u + (unsigned int)scap) {
    ws[SPILL_OFF + (size_t)cell * scap + (pos - 3u)] = (unsigned int)r;
  } else {
    unsigned int o = atomicAdd(&ws[OVF_HDR], 1u);
    if (o < (unsigned int)OVF_MAX) {
      ws[OVF_LIST + 2 * o + 0] = (unsigned int)cell;
      ws[OVF_LIST + 2 * o + 1] = (unsigned int)r;
    }
  }
}

__device__ __forceinline__ void fmax4(float4& a, float4 v) {
  a.x = fmaxf(a.x, v.x);
  a.y = fmaxf(a.y, v.y);
  a.z = fmaxf(a.z, v.z);
  a.w = fmaxf(a.w, v.w);
}

// CPT tasks per thread, strided by N so each group of 16 consecutive threads
// shares one cell (coalesced 256 B emb reads and out writes). 4 independent
// header chains per thread for MLP.
constexpr int CPT = 4;
__global__ void ga_gather(const float4* __restrict__ emb4,
                          const uint4* __restrict__ hdr,
                          const unsigned int* __restrict__ spill,
                          float4* __restrict__ out4, int scap) {
  const int N = NCELLS * 16 / CPT;                 // 1,280,000 threads
  int t = blockIdx.x * blockDim.x + threadIdx.x;
  if (t >= N) return;
  uint4 h[CPT];
  int cell0 = t >> 4;
  int sub   = t & 15;                              // same sub for all k
#pragma unroll
  for (int k = 0; k < CPT; ++k)
    h[k] = hdr[cell0 + k * (NCELLS / CPT)];
#pragma unroll
  for (int k = 0; k < CPT; ++k) {
    int cell = cell0 + k * (NCELLS / CPT);
    unsigned int c = h[k].x;
    float4 acc = make_float4(0.f, 0.f, 0.f, 0.f);
    if (c != 0u) {
      float ninf = -__builtin_inff();
      acc = make_float4(ninf, ninf, ninf, ninf);
      // header rows, predicated (no runtime-indexed local array)
      float4 v0 = emb4[(size_t)h[k].y * 16 + sub];
      fmax4(acc, v0);
      if (c >= 2u) fmax4(acc, emb4[(size_t)h[k].z * 16 + sub]);
      if (c >= 3u) fmax4(acc, emb4[(size_t)h[k].w * 16 + sub]);
      if (c > 3u) {                                // rare spill path (~1%)
        int n1 = (int)c - 3; if (n1 > scap) n1 = scap;
        const unsigned int* sp = spill + (size_t)cell * scap;
        for (int j = 0; j < n1; ++j)
          fmax4(acc, emb4[(size_t)sp[j] * 16 + sub]);
      }
    }
    out4[(size_t)cell * 16 + sub] = acc;
  }
}

__device__ __forceinline__ void atomic_max_float(float* addr, float val) {
  unsigned int* ua = (unsigned int*)addr;
  unsigned int old = *ua;
  while (__uint_as_float(old) < val) {
    unsigned int assumed = old;
    old = atomicCAS(ua, assumed, __float_as_uint(val));
    if (old == assumed) break;
  }
}

// Drain overflow entries (expected: none to a handful).
__global__ void ga_ovf(const float4* __restrict__ emb4,
                       const unsigned int* __restrict__ ws,
                       float* __restrict__ out) {
  unsigned int nov = ws[OVF_HDR];
  if (nov > (unsigned int)OVF_MAX) nov = OVF_MAX;
  int total = (int)nov * 16;
  int stride = gridDim.x * blockDim.x;
  for (int u = blockIdx.x * blockDim.x + threadIdx.x; u < total; u += stride) {
    int e = u >> 4, sub = u & 15;
    unsigned int cell = ws[OVF_LIST + 2 * e + 0];
    unsigned int row  = ws[OVF_LIST + 2 * e + 1];
    float4 v = emb4[(size_t)row * 16 + sub];
    float* o = out + (size_t)cell * 64 + sub * 4;
    atomic_max_float(o + 0, v.x);
    atomic_max_float(o + 1, v.y);
    atomic_max_float(o + 2, v.z);
    atomic_max_float(o + 3, v.w);
  }
}

// ------------------------- legacy atomic path (ws too small) -----------------
__device__ __forceinline__ unsigned int enc_f32(float f) {
  unsigned int u = __float_as_uint(f);
  return (u & 0x80000000u) ? ~u : (u | 0x80000000u);
}
__device__ __forceinline__ float dec_f32(unsigned int e) {
  unsigned int u = (e & 0x80000000u) ? (e ^ 0x80000000u) : ~e;
  return __uint_as_float(u);
}

__global__ void ga_init(uint4* __restrict__ out4, int n4) {
  int stride = gridDim.x * blockDim.x;
  for (int i = blockIdx.x * blockDim.x + threadIdx.x; i < n4; i += stride)
    out4[i] = make_uint4(0u, 0u, 0u, 0u);
}

__global__ void ga_scatter(const float4* __restrict__ emb4,
                           const int* __restrict__ gene_ids,
                           const int* __restrict__ mask,
                           unsigned int* __restrict__ out) {
  int tid = blockIdx.x * blockDim.x + threadIdx.x;
  int v  = tid >> 4;
  int dq = tid & 15;
  if (!mask[v]) return;
  int g = gene_ids[v];
  int b = v >> 14;
  float4 e = emb4[tid];
  int base = (b * G + g) * D + (dq << 2);
  atomicMax(out + base + 0, enc_f32(e.x));
  atomicMax(out + base + 1, enc_f32(e.y));
  atomicMax(out + base + 2, enc_f32(e.z));
  atomicMax(out + base + 3, enc_f32(e.w));
}

__global__ void ga_finalize(uint4* __restrict__ io4, int n4) {
  int stride = gridDim.x * blockDim.x;
  for (int i = blockIdx.x * blockDim.x + threadIdx.x; i < n4; i += stride) {
    uint4 e = io4[i];
    float4 f;
    f.x = e.x ? dec_f32(e.x) : 0.0f;
    f.y = e.y ? dec_f32(e.y) : 0.0f;
    f.z = e.z ? dec_f32(e.z) : 0.0f;
    f.w = e.w ? dec_f32(e.w) : 0.0f;
    *reinterpret_cast<float4*>(io4 + i) = f;
  }
}

// -----------------------------------------------------------------------------
extern "C" void kernel_launch(void* const* d_in, const int* in_sizes, int n_in,
                              void* d_out, int out_size, void* d_ws, size_t ws_size,
                              hipStream_t stream) {
  const float4* emb4     = (const float4*)d_in[0];   // [B,V,D] f32
  const int*    gene_ids = (const int*)d_in[1];      // [B,V]
  const int*    mask     = (const int*)d_in[2];      // [B,V]

  long long ws_u32 = (long long)(ws_size / 4);
  long long avail  = ws_u32 - (long long)SPILL_OFF;
  int scap = (int)(avail > 0 ? avail / NCELLS : -1);
  if (scap > 13) scap = 13;

  if (scap >= 0) {
    unsigned int* ws = (unsigned int*)d_ws;
    ga_zero<<<1024, 256, 0, stream>>>((uint4*)d_ws, ws);
    ga_build<<<NROWS / 256, 256, 0, stream>>>(gene_ids, mask, ws, scap);
    const int N = NCELLS * 16 / CPT;                 // 1,280,000
    ga_gather<<<N / 256, 256, 0, stream>>>(
        emb4, (const uint4*)d_ws, ws + SPILL_OFF, (float4*)d_out, scap);
    ga_ovf<<<64, 256, 0, stream>>>(emb4, ws, (float*)d_out);
  } else {
    // Fallback: direct atomic scatter-max (round-1 passing version).
    unsigned int* out_u = (unsigned int*)d_out;
    const int n4 = (int)(OUT_N / 4);
    ga_init<<<2048, 256, 0, stream>>>((uint4*)d_out, n4);
    ga_scatter<<<(NROWS * 16) / 256, 256, 0, stream>>>(emb4, gene_ids, mask, out_u);
    ga_finalize<<<2048, 256, 0, stream>>>((uint4*)d_out, n4);
  }
}